// Round 9
// baseline (136.178 us; speedup 1.0000x reference)
//
#include <hip/hip_runtime.h>
#include <stdint.h>

// BacklashNet: per-row nonlinear scan (backlash/hysteresis).
// WAVE-PER-ROW, ZERO-BARRIER streaming design. R9 = R8 + deep prologue
// prefetch (triple buffer) + register-resident x between passes.
//
// History:
//  R1 70us block/row fused; R2 97us reg-prefetch spill; R3 42.8us dbuf
//  (syncthreads drains vmcnt); R4 NULL (clobber re-drained); R5 99.9us
//  (sched_barrier pins); R6 82.5us (VGPR-128 spill); R7 46us (spill fixed,
//  still ~2.2TB/s: barrier phase-lock); R8 ~31.5us (kernel dropped below
//  the 41us harness fills): wave-per-row, zero barriers, shfl comms.
//
//  R8 residual analysis: steady state is memory-saturated (compute
//  ~1.2us/seg << 5.2us fair-share BW/seg/CU); the ~10us over the ~21us
//  traffic floor is RAMP (fetch(1) only issued after stage(0)'s wait, so
//  first ~5us run at half MLP) + un-overlapped final flush.
//
// R9:
//  - prologue: fetch(0); fetch(1); THEN stage(0). Both segments' 16KB are
//    in flight from t=0 -> reads saturate immediately.
//  - triple-buffer A,B,C: fetch(i+2) issued before proc(i); stage(i)'s
//    wait is for loads issued two compute-phases earlier.
//  - xv kept in VGPRs across passA/passB (LDS ops 40->32/seg; passB needs
//    no re-read). Cap 256 VGPR at launch_bounds(64,2); est ~170 used.
//  - everything else byte-identical to R8 (passed, absmax 7.8e-3):
//    swizzle slot(c,f)=c*8+(f^(c&7)) (uniform bank-group spread), bstep
//    bit-exact __f*_rn reference order, per-segment ballot acceptance
//    (chunk0 from TRUE t; all pa==pb -> pass-B outputs exact), rare
//    in-wave stitch replaying from global x.

namespace {

constexpr int kT   = 8192;
constexpr int kSeg = 2048;           // elements per segment
constexpr int kF4  = kSeg / 4;       // 512 float4 slots (8 KB)

__device__ __forceinline__ float bstep(float xv, float prev, float m_lo, float m_up,
                                       float mlc, float muc) {
  float A1 = __fmul_rn(m_lo, xv);
  float B1 = __fadd_rn(A1, mlc);
  float A2 = __fmul_rn(m_up, xv);
  float B2 = __fadd_rn(A2, muc);
  float C  = __fadd_rn(__fadd_rn(B1, A2), muc);
  float u  = __fsub_rn(prev, A2);
  bool  f1 = (B1 <= prev);
  bool  f2 = (u <= muc);
  float hi = f2 ? C  : B1;
  float lo = f2 ? B2 : prev;
  return f1 ? hi : lo;
}

// Coalesced fetch of one segment into a register buffer (8 x 1KB/wave).
__device__ __forceinline__ void seg_fetch(const float4* __restrict__ xr, int seg,
                                          int l, float4 (&buf)[8]) {
#pragma unroll
  for (int j = 0; j < 8; ++j) buf[j] = xr[seg * kF4 + j * 64 + l];
}

// Stage registers -> swizzled LDS transpose. Global float4 g=(j*64+l):
// chunk c=g>>3, frag f=g&7, slot = c*8 + (f^(c&7)).
// Bank group of slot = (l&7)^((l>>3)&7): uniform over 64 lanes.
__device__ __forceinline__ void seg_stage(float4* __restrict__ sb, int l,
                                          const float4 (&buf)[8]) {
#pragma unroll
  for (int j = 0; j < 8; ++j) {
    const int g = j * 64 + l, c = g >> 3, f = g & 7;
    sb[c * 8 + (f ^ (c & 7))] = buf[j];
  }
}

// Process one staged segment; returns the new carried row state.
__device__ __forceinline__ float process_seg(
    float4* __restrict__ sb, const float* __restrict__ x,
    float4* __restrict__ o4, int r, int seg, int l, float t,
    float m_lo, float m_up, float mlc, float muc) {
  // my chunk -> registers once; both passes consume from VGPRs
  float4 xv[8];
#pragma unroll
  for (int f = 0; f < 8; ++f) xv[f] = sb[l * 8 + (f ^ (l & 7))];

  // pass A: from guess (true t for chunk 0, else 0)
  float pa = (l == 0) ? t : 0.0f;
#pragma unroll
  for (int f = 0; f < 8; ++f) {
    pa = bstep(xv[f].x, pa, m_lo, m_up, mlc, muc);
    pa = bstep(xv[f].y, pa, m_lo, m_up, mlc, muc);
    pa = bstep(xv[f].z, pa, m_lo, m_up, mlc, muc);
    pa = bstep(xv[f].w, pa, m_lo, m_up, mlc, muc);
  }

  // pass B: from neighbor's pass-A exit (true t for chunk 0); outputs
  // overwrite the x slots in LDS (lane-private slot set).
  float ent = __shfl_up(pa, 1);
  if (l == 0) ent = t;
  float pb = ent;
#pragma unroll
  for (int f = 0; f < 8; ++f) {
    float o0 = bstep(xv[f].x, pb, m_lo, m_up, mlc, muc);
    float o1 = bstep(xv[f].y, o0, m_lo, m_up, mlc, muc);
    float o2 = bstep(xv[f].z, o1, m_lo, m_up, mlc, muc);
    float o3 = bstep(xv[f].w, o2, m_lo, m_up, mlc, muc);
    sb[l * 8 + (f ^ (l & 7))] = make_float4(o0, o1, o2, o3);
    pb = o3;
  }

  // acceptance: chunk c+1's pass-B entry (=pa[c]) is true iff pa[c]==pb[c]
  const bool conv = (pa == pb) || (l == 63);
  if (__ballot(conv) == ~0ull) {
    t = __shfl(pb, 63);             // all exact: carried state = pb[63]
  } else {
    // Rare exact stitch, fully in-wave (uniform branches via shfl
    // broadcasts). LDS holds outputs, so replay reads global x.
    float tc = __shfl(pb, 0);       // chunk 0 ran from true t
    for (int cc = 1; cc < 64; ++cc) {
      const float used = __shfl(pa, cc - 1);   // pass-B entry of chunk cc
      if (used == tc) {
        tc = __shfl(pb, cc);
      } else {
        float pf = tc;
        if (l == cc) {
          const float4* xg = reinterpret_cast<const float4*>(
              x + (size_t)r * kT + seg * kSeg + cc * 32);
#pragma unroll
          for (int f = 0; f < 8; ++f) {
            const float4 xw = xg[f];
            float o0 = bstep(xw.x, pf, m_lo, m_up, mlc, muc);
            float o1 = bstep(xw.y, o0, m_lo, m_up, mlc, muc);
            float o2 = bstep(xw.z, o1, m_lo, m_up, mlc, muc);
            float o3 = bstep(xw.w, o2, m_lo, m_up, mlc, muc);
            sb[l * 8 + (f ^ (l & 7))] = make_float4(o0, o1, o2, o3);
            pf = o3;
          }
        }
        tc = __shfl(pf, cc);
      }
    }
    t = tc;
  }

  // coalesced flush: LDS -> out, 8 x 1KB/wave store instructions
#pragma unroll
  for (int j = 0; j < 8; ++j) {
    const int g = j * 64 + l, c = g >> 3, f = g & 7;
    o4[seg * kF4 + g] = sb[c * 8 + (f ^ (c & 7))];
  }
  return t;
}

__global__ __launch_bounds__(64, 2) void backlash_wave(
    const float* __restrict__ x, const float* __restrict__ p0,
    const float* __restrict__ w, float* __restrict__ out) {
  __shared__ float4 sb[kF4];           // 8 KB wave-private transpose buffer

  const int l = threadIdx.x;
  const int r = blockIdx.x;
  const float4* xr = reinterpret_cast<const float4*>(x + (size_t)r * kT);
  float4* o4 = reinterpret_cast<float4*>(out + (size_t)r * kT);

  float4 A[8], B[8], C[8];

  // prologue: TWO segments in flight before any wait (ramp at full MLP)
  seg_fetch(xr, 0, l, A);
  seg_fetch(xr, 1, l, B);

  const float m_lo = w[0], m_up = w[1];
  const float mlc = __fmul_rn(m_lo, w[2]), muc = __fmul_rn(m_up, w[3]);
  float t = p0[r];

  seg_stage(sb, l, A);                 // waits loads(0); loads(1) in flight
  seg_fetch(xr, 2, l, C);              // third buffer: 2 segments ahead
  t = process_seg(sb, x, o4, r, 0, l, t, m_lo, m_up, mlc, muc);

  seg_stage(sb, l, B);                 // waits loads(1), issued 2 phases ago
  seg_fetch(xr, 3, l, A);              // reuse A
  t = process_seg(sb, x, o4, r, 1, l, t, m_lo, m_up, mlc, muc);

  seg_stage(sb, l, C);
  t = process_seg(sb, x, o4, r, 2, l, t, m_lo, m_up, mlc, muc);

  seg_stage(sb, l, A);
  t = process_seg(sb, x, o4, r, 3, l, t, m_lo, m_up, mlc, muc);
}

}  // namespace

extern "C" void kernel_launch(void* const* d_in, const int* in_sizes, int n_in,
                              void* d_out, int out_size, void* d_ws, size_t ws_size,
                              hipStream_t stream) {
  const float* x  = (const float*)d_in[0];   // (B, T, 1) fp32
  const float* p0 = (const float*)d_in[1];   // (B, 1, 1) fp32
  const float* w  = (const float*)d_in[2];   // (4,) fp32
  float* out = (float*)d_out;                // (B, T, 1) fp32
  (void)in_sizes; (void)n_in; (void)out_size; (void)d_ws; (void)ws_size;

  backlash_wave<<<2048, 64, 0, stream>>>(x, p0, w, out);
}

// Round 10
// 135.738 us; speedup vs baseline: 1.0032x; 1.0032x over previous
//
#include <hip/hip_runtime.h>
#include <stdint.h>

// BacklashNet: per-row nonlinear scan (backlash/hysteresis).
// WAVE-PER-ROW, ZERO-BARRIER streaming. R10 = R8 + early-prologue fetch
// (2 segments in flight from t=0), double-buffer ONLY (no spill).
//
// History:
//  R1 70us block/row fused; R2 97us reg-prefetch SPILL; R3 42.8us dbuf
//  (syncthreads drains vmcnt); R4 NULL (clobber re-drained); R5 99.9us
//  (sched_barrier pins); R6 82.5us VGPR-128 SPILL; R7 46us (spill fixed,
//  ~2.2TB/s barrier phase-lock); R8 ~30.5us wave-per-row zero-barrier
//  (best); R9 51us SPILL #3 (3 bufs + xv regs: VGPR 84, WRITE +48MB,
//  FETCH +16MB scratch).
//
//  Compiler rule learned (R2/R6/R9): register staging beyond TWO 32-VGPR
//  buffers spills. R8's A/B double-buffer is the proven budget (~100 VGPR).
//
// R10 (only change vs R8): prologue issues fetch(0) AND fetch(1) before
//  stage(0)'s wait -> full MLP during ramp; steady-state stage(i) waits on
//  loads issued >=1 full phase earlier. Buffer reuse A,B,A,B.
//
// Verified machinery byte-identical to R8 (passed, absmax 7.8e-3):
//  - swizzle slot(c,f)=c*8+(f^(c&7)): every ds phase spreads 64 lanes
//    uniformly over the 8 four-bank groups (conflict-free b128)
//  - bstep bit-exact (__f*_rn, reference op order)
//  - per-segment ballot acceptance: chunk 0 runs from TRUE carried t;
//    all pa==pb -> pass-B outputs exact, t' = pb[63]; rare failure ->
//    in-wave stitch (shfl-broadcast uniform branches, replay from global)
//  - 1 wave/block: LDS wave-private, ds ops wave-ordered -> flush reads
//    always precede next stage writes, no barrier needed anywhere.

namespace {

constexpr int kT   = 8192;
constexpr int kSeg = 2048;           // elements per segment
constexpr int kF4  = kSeg / 4;       // 512 float4 slots (8 KB)

__device__ __forceinline__ float bstep(float xv, float prev, float m_lo, float m_up,
                                       float mlc, float muc) {
  float A1 = __fmul_rn(m_lo, xv);
  float B1 = __fadd_rn(A1, mlc);
  float A2 = __fmul_rn(m_up, xv);
  float B2 = __fadd_rn(A2, muc);
  float C  = __fadd_rn(__fadd_rn(B1, A2), muc);
  float u  = __fsub_rn(prev, A2);
  bool  f1 = (B1 <= prev);
  bool  f2 = (u <= muc);
  float hi = f2 ? C  : B1;
  float lo = f2 ? B2 : prev;
  return f1 ? hi : lo;
}

// Coalesced fetch of one segment into a register buffer (8 x 1KB/wave).
__device__ __forceinline__ void seg_fetch(const float4* __restrict__ xr, int seg,
                                          int l, float4 (&buf)[8]) {
#pragma unroll
  for (int j = 0; j < 8; ++j) buf[j] = xr[seg * kF4 + j * 64 + l];
}

// Stage registers -> swizzled LDS transpose. Global float4 g=(j*64+l):
// chunk c=g>>3, frag f=g&7, slot = c*8 + (f^(c&7)).
__device__ __forceinline__ void seg_stage(float4* __restrict__ sb, int l,
                                          const float4 (&buf)[8]) {
#pragma unroll
  for (int j = 0; j < 8; ++j) {
    const int g = j * 64 + l, c = g >> 3, f = g & 7;
    sb[c * 8 + (f ^ (c & 7))] = buf[j];
  }
}

// Process one staged segment; returns the new carried row state.
__device__ __forceinline__ float process_seg(
    float4* __restrict__ sb, const float* __restrict__ x,
    float4* __restrict__ o4, int r, int seg, int l, float t,
    float m_lo, float m_up, float mlc, float muc) {
  // pass A: from guess (true t for chunk 0, else 0); x read in-loop
  float pa = (l == 0) ? t : 0.0f;
#pragma unroll
  for (int f = 0; f < 8; ++f) {
    const float4 xv = sb[l * 8 + (f ^ (l & 7))];
    pa = bstep(xv.x, pa, m_lo, m_up, mlc, muc);
    pa = bstep(xv.y, pa, m_lo, m_up, mlc, muc);
    pa = bstep(xv.z, pa, m_lo, m_up, mlc, muc);
    pa = bstep(xv.w, pa, m_lo, m_up, mlc, muc);
  }

  // pass B: from neighbor's pass-A exit (true t for chunk 0); outputs
  // overwrite the x slots in LDS (lane-private slot set).
  float ent = __shfl_up(pa, 1);
  if (l == 0) ent = t;
  float pb = ent;
#pragma unroll
  for (int f = 0; f < 8; ++f) {
    const int slot = l * 8 + (f ^ (l & 7));
    const float4 xv = sb[slot];
    float o0 = bstep(xv.x, pb, m_lo, m_up, mlc, muc);
    float o1 = bstep(xv.y, o0, m_lo, m_up, mlc, muc);
    float o2 = bstep(xv.z, o1, m_lo, m_up, mlc, muc);
    float o3 = bstep(xv.w, o2, m_lo, m_up, mlc, muc);
    sb[slot] = make_float4(o0, o1, o2, o3);
    pb = o3;
  }

  // acceptance: chunk c+1's pass-B entry (=pa[c]) is true iff pa[c]==pb[c]
  const bool conv = (pa == pb) || (l == 63);
  if (__ballot(conv) == ~0ull) {
    t = __shfl(pb, 63);             // all exact: carried state = pb[63]
  } else {
    // Rare exact stitch, fully in-wave (uniform branches via shfl
    // broadcasts). LDS holds outputs, so replay reads global x.
    float tc = __shfl(pb, 0);       // chunk 0 ran from true t
    for (int cc = 1; cc < 64; ++cc) {
      const float used = __shfl(pa, cc - 1);   // pass-B entry of chunk cc
      if (used == tc) {
        tc = __shfl(pb, cc);
      } else {
        float pf = tc;
        if (l == cc) {
          const float4* xg = reinterpret_cast<const float4*>(
              x + (size_t)r * kT + seg * kSeg + cc * 32);
#pragma unroll
          for (int f = 0; f < 8; ++f) {
            const float4 xw = xg[f];
            float o0 = bstep(xw.x, pf, m_lo, m_up, mlc, muc);
            float o1 = bstep(xw.y, o0, m_lo, m_up, mlc, muc);
            float o2 = bstep(xw.z, o1, m_lo, m_up, mlc, muc);
            float o3 = bstep(xw.w, o2, m_lo, m_up, mlc, muc);
            sb[l * 8 + (f ^ (l & 7))] = make_float4(o0, o1, o2, o3);
            pf = o3;
          }
        }
        tc = __shfl(pf, cc);
      }
    }
    t = tc;
  }

  // coalesced flush: LDS -> out, 8 x 1KB/wave store instructions
#pragma unroll
  for (int j = 0; j < 8; ++j) {
    const int g = j * 64 + l, c = g >> 3, f = g & 7;
    o4[seg * kF4 + g] = sb[c * 8 + (f ^ (c & 7))];
  }
  return t;
}

__global__ __launch_bounds__(64, 2) void backlash_wave(
    const float* __restrict__ x, const float* __restrict__ p0,
    const float* __restrict__ w, float* __restrict__ out) {
  __shared__ float4 sb[kF4];           // 8 KB wave-private transpose buffer

  const int l = threadIdx.x;
  const int r = blockIdx.x;
  const float4* xr = reinterpret_cast<const float4*>(x + (size_t)r * kT);
  float4* o4 = reinterpret_cast<float4*>(out + (size_t)r * kT);

  float4 A[8], B[8];                   // TWO buffers only (spill rule)

  // prologue: both segments 0 and 1 in flight before any wait
  seg_fetch(xr, 0, l, A);
  seg_fetch(xr, 1, l, B);

  const float m_lo = w[0], m_up = w[1];
  const float mlc = __fmul_rn(m_lo, w[2]), muc = __fmul_rn(m_up, w[3]);
  float t = p0[r];

  seg_stage(sb, l, A);                 // counted wait on loads(0) only
  seg_fetch(xr, 2, l, A);              // reuse A immediately (regs dead)
  t = process_seg(sb, x, o4, r, 0, l, t, m_lo, m_up, mlc, muc);

  seg_stage(sb, l, B);                 // loads(1) issued at t=0: no stall
  seg_fetch(xr, 3, l, B);              // reuse B
  t = process_seg(sb, x, o4, r, 1, l, t, m_lo, m_up, mlc, muc);

  seg_stage(sb, l, A);                 // loads(2) issued one phase ago
  t = process_seg(sb, x, o4, r, 2, l, t, m_lo, m_up, mlc, muc);

  seg_stage(sb, l, B);                 // loads(3) issued one phase ago
  t = process_seg(sb, x, o4, r, 3, l, t, m_lo, m_up, mlc, muc);
}

}  // namespace

extern "C" void kernel_launch(void* const* d_in, const int* in_sizes, int n_in,
                              void* d_out, int out_size, void* d_ws, size_t ws_size,
                              hipStream_t stream) {
  const float* x  = (const float*)d_in[0];   // (B, T, 1) fp32
  const float* p0 = (const float*)d_in[1];   // (B, 1, 1) fp32
  const float* w  = (const float*)d_in[2];   // (4,) fp32
  float* out = (float*)d_out;                // (B, T, 1) fp32
  (void)in_sizes; (void)n_in; (void)out_size; (void)d_ws; (void)ws_size;

  backlash_wave<<<2048, 64, 0, stream>>>(x, p0, w, out);
}